// Round 1
// baseline (23217.813 us; speedup 1.0000x reference)
//
#include <hip/hip_runtime.h>
#include <cstddef>

#define S_LEN 2048
#define B_SZ  64
#define I_DIM 256
#define H_DIM 512

// ---------------------------------------------------------------------------
// Kernel A: projection GEMM.
//   out[m, n] = sum_k X[m,k] * W[n,k] + b_ih[n] + b_hh[n]
// X = x_in viewed [M=B*S, K=256] (row-major, m = b*S+s), W = W_ih [512, 256].
// Output written straight into d_out ([B,S,H] flat == [M, H]).
// Classic 64x64 tile, BK=32, 256 threads, 4x4 per thread, fp32.
// ---------------------------------------------------------------------------
#define BM 64
#define BN 64
#define BK 32

__global__ __launch_bounds__(256) void proj_gemm(
        const float* __restrict__ X, const float* __restrict__ W,
        const float* __restrict__ b_ih, const float* __restrict__ b_hh,
        float* __restrict__ out) {
    __shared__ float As[BK][BM + 4];   // +4 keeps 16B alignment, breaks conflicts
    __shared__ float Bs[BK][BN + 4];

    const int t    = threadIdx.x;
    const int row0 = blockIdx.y * BM;
    const int col0 = blockIdx.x * BN;
    const int ty   = t >> 4;    // 0..15  (m group)
    const int tx   = t & 15;    // 0..15  (n group)

    float acc[4][4];
#pragma unroll
    for (int i = 0; i < 4; ++i)
#pragma unroll
        for (int j = 0; j < 4; ++j) acc[i][j] = 0.f;

    for (int kb = 0; kb < I_DIM; kb += BK) {
        // Load A tile (64m x 32k) and B tile (64n x 32k): 512 float4 each,
        // 2 per thread per tile. idx -> m = idx/8, k4 = idx%8.
#pragma unroll
        for (int r = 0; r < 2; ++r) {
            const int idx = t + r * 256;
            const int m   = idx >> 3;
            const int k4  = idx & 7;
            float4 va = *(const float4*)(X + (size_t)(row0 + m) * I_DIM + kb + k4 * 4);
            As[k4 * 4 + 0][m] = va.x;
            As[k4 * 4 + 1][m] = va.y;
            As[k4 * 4 + 2][m] = va.z;
            As[k4 * 4 + 3][m] = va.w;
            float4 vb = *(const float4*)(W + (size_t)(col0 + m) * I_DIM + kb + k4 * 4);
            Bs[k4 * 4 + 0][m] = vb.x;
            Bs[k4 * 4 + 1][m] = vb.y;
            Bs[k4 * 4 + 2][m] = vb.z;
            Bs[k4 * 4 + 3][m] = vb.w;
        }
        __syncthreads();
#pragma unroll
        for (int kk = 0; kk < BK; ++kk) {
            float4 a = *(const float4*)&As[kk][ty * 4];
            float4 b = *(const float4*)&Bs[kk][tx * 4];
            const float av[4] = {a.x, a.y, a.z, a.w};
            const float bv[4] = {b.x, b.y, b.z, b.w};
#pragma unroll
            for (int i = 0; i < 4; ++i)
#pragma unroll
                for (int j = 0; j < 4; ++j)
                    acc[i][j] = fmaf(av[i], bv[j], acc[i][j]);
        }
        __syncthreads();
    }

    // Epilogue: add biases, coalesced float4 stores.
    float bias[4];
#pragma unroll
    for (int j = 0; j < 4; ++j) {
        const int n = col0 + tx * 4 + j;
        bias[j] = b_ih[n] + b_hh[n];
    }
#pragma unroll
    for (int i = 0; i < 4; ++i) {
        const int m = row0 + ty * 4 + i;
        float4 o;
        o.x = acc[i][0] + bias[0];
        o.y = acc[i][1] + bias[1];
        o.z = acc[i][2] + bias[2];
        o.w = acc[i][3] + bias[3];
        *(float4*)(out + (size_t)m * H_DIM + col0 + tx * 4) = o;
    }
}

// ---------------------------------------------------------------------------
// Kernel A2: transpose W_hh [512,512] -> Wt[k][j] = W_hh[j][k] in d_ws,
// so the scan's k-loop reads are lane-coalesced.
// ---------------------------------------------------------------------------
__global__ __launch_bounds__(256) void transpose512(
        const float* __restrict__ W, float* __restrict__ Wt) {
    __shared__ float tile[32][33];
    const int bx = blockIdx.x * 32;
    const int by = blockIdx.y * 32;
    const int tx = threadIdx.x;   // 0..31
    const int ty = threadIdx.y;   // 0..7
#pragma unroll
    for (int r = 0; r < 32; r += 8)
        tile[ty + r][tx] = W[(size_t)(by + ty + r) * H_DIM + bx + tx];
    __syncthreads();
#pragma unroll
    for (int r = 0; r < 32; r += 8)
        Wt[(size_t)(bx + ty + r) * H_DIM + by + tx] = tile[tx][ty + r];
}

// ---------------------------------------------------------------------------
// Kernel B: the sequential scan. One workgroup per batch row (64 wgs).
// 512 threads; thread j owns output unit j. h kept in LDS (double-buffered,
// one barrier per step). d_out holds x_proj on entry and is overwritten
// in place with the hidden states.
//   h_new[j] = tanh(xp[s,j] + sum_k Wt[k*512+j] * h[k])
// ---------------------------------------------------------------------------
__global__ __launch_bounds__(512) void rnn_scan(
        const float* __restrict__ Wt, const float* __restrict__ h0,
        float* __restrict__ out) {
    const int b = blockIdx.x;
    const int j = threadIdx.x;
    __shared__ float hbuf[2][H_DIM];

    hbuf[0][j] = h0[(size_t)b * H_DIM + j];
    __syncthreads();

    float* outb = out + (size_t)b * S_LEN * H_DIM;
    int p = 0;
    for (int s = 0; s < S_LEN; ++s) {
        const float xp = outb[(size_t)s * H_DIM + j];
        const float* hp = hbuf[p];
        float acc = 0.f;
#pragma unroll 8
        for (int k = 0; k < H_DIM; ++k)
            acc = fmaf(Wt[(size_t)k * H_DIM + j], hp[k], acc);
        const float hn = tanhf(xp + acc);
        outb[(size_t)s * H_DIM + j] = hn;
        hbuf[p ^ 1][j] = hn;
        __syncthreads();
        p ^= 1;
    }
}

// ---------------------------------------------------------------------------
extern "C" void kernel_launch(void* const* d_in, const int* in_sizes, int n_in,
                              void* d_out, int out_size, void* d_ws, size_t ws_size,
                              hipStream_t stream) {
    const float* x_in = (const float*)d_in[0];
    const float* h0   = (const float*)d_in[1];
    const float* W_ih = (const float*)d_in[2];
    const float* W_hh = (const float*)d_in[3];
    const float* b_ih = (const float*)d_in[4];
    const float* b_hh = (const float*)d_in[5];
    float* out = (float*)d_out;
    float* Wt  = (float*)d_ws;            // 512*512*4 = 1 MB scratch

    // 1) x_proj (+biases) into d_out:  grid (512/64, 131072/64) = (8, 2048)
    dim3 gA(H_DIM / BN, (B_SZ * S_LEN) / BM);
    proj_gemm<<<gA, 256, 0, stream>>>(x_in, W_ih, b_ih, b_hh, out);

    // 2) W_hh^T into workspace
    transpose512<<<dim3(16, 16), dim3(32, 8), 0, stream>>>(W_hh, Wt);

    // 3) sequential scan, in place over d_out
    rnn_scan<<<B_SZ, H_DIM, 0, stream>>>(Wt, h0, out);
}

// Round 4
// 4464.536 us; speedup vs baseline: 5.2005x; 5.2005x over previous
//
#include <hip/hip_runtime.h>
#include <cstddef>

#define S_LEN 2048
#define B_SZ  64
#define I_DIM 256
#define H_DIM 512

// ---------------------------------------------------------------------------
// Kernel A: projection GEMM (unchanged — validated in round 1).
//   out[m, n] = sum_k X[m,k] * W_ih[n,k] + b_ih[n] + b_hh[n]
// ---------------------------------------------------------------------------
#define BM 64
#define BN 64
#define BK 32

__global__ __launch_bounds__(256) void proj_gemm(
        const float* __restrict__ X, const float* __restrict__ W,
        const float* __restrict__ b_ih, const float* __restrict__ b_hh,
        float* __restrict__ out) {
    __shared__ float As[BK][BM + 4];
    __shared__ float Bs[BK][BN + 4];

    const int t    = threadIdx.x;
    const int row0 = blockIdx.y * BM;
    const int col0 = blockIdx.x * BN;
    const int ty   = t >> 4;
    const int tx   = t & 15;

    float acc[4][4];
#pragma unroll
    for (int i = 0; i < 4; ++i)
#pragma unroll
        for (int j = 0; j < 4; ++j) acc[i][j] = 0.f;

    for (int kb = 0; kb < I_DIM; kb += BK) {
#pragma unroll
        for (int r = 0; r < 2; ++r) {
            const int idx = t + r * 256;
            const int m   = idx >> 3;
            const int k4  = idx & 7;
            float4 va = *(const float4*)(X + (size_t)(row0 + m) * I_DIM + kb + k4 * 4);
            As[k4 * 4 + 0][m] = va.x;
            As[k4 * 4 + 1][m] = va.y;
            As[k4 * 4 + 2][m] = va.z;
            As[k4 * 4 + 3][m] = va.w;
            float4 vb = *(const float4*)(W + (size_t)(col0 + m) * I_DIM + kb + k4 * 4);
            Bs[k4 * 4 + 0][m] = vb.x;
            Bs[k4 * 4 + 1][m] = vb.y;
            Bs[k4 * 4 + 2][m] = vb.z;
            Bs[k4 * 4 + 3][m] = vb.w;
        }
        __syncthreads();
#pragma unroll
        for (int kk = 0; kk < BK; ++kk) {
            float4 a = *(const float4*)&As[kk][ty * 4];
            float4 b = *(const float4*)&Bs[kk][tx * 4];
            const float av[4] = {a.x, a.y, a.z, a.w};
            const float bv[4] = {b.x, b.y, b.z, b.w};
#pragma unroll
            for (int i = 0; i < 4; ++i)
#pragma unroll
                for (int j = 0; j < 4; ++j)
                    acc[i][j] = fmaf(av[i], bv[j], acc[i][j]);
        }
        __syncthreads();
    }

    float bias[4];
#pragma unroll
    for (int j = 0; j < 4; ++j) {
        const int n = col0 + tx * 4 + j;
        bias[j] = b_ih[n] + b_hh[n];
    }
#pragma unroll
    for (int i = 0; i < 4; ++i) {
        const int m = row0 + ty * 4 + i;
        float4 o;
        o.x = acc[i][0] + bias[0];
        o.y = acc[i][1] + bias[1];
        o.z = acc[i][2] + bias[2];
        o.w = acc[i][3] + bias[3];
        *(float4*)(out + (size_t)m * H_DIM + col0 + tx * 4) = o;
    }
}

// ---------------------------------------------------------------------------
// Kernel B: register-resident-W scan. Cross-wg exchange via atomicExch-only
// single-reader mailboxes.
//
// Round-3 post-mortem: atomicAdd(p,0) polls were InstCombine'd into atomic
// LOADS, served stale-SENT from the consumer's non-coherent per-XCD L2; all
// wgs bailed instantly and computed tanh(xp) (absmax 1.695 < 2 = bounded
// output, near-zero extra wall time — the smoking gun). Fix: atomicExch on
// BOTH sides — never idempotent, always a genuine global_atomic_swap at the
// device coherence point (the m20-verified primitive class).
//
// Protocol: mb[phase(2)][cons_slice(4)][b][col(512)], pre-armed SENT
// (0xAAAAAAAA — also the harness ws poison). Producer wg (slice p, batch b)
// at step s publishes h_s[col] to all 4 consumer mailboxes of phase s&1 via
// atomicExch. Consumer wg c at step s+1 polls its own mailbox entries with
// v = atomicExch(src, SENT): returns SENT (spin) or the fresh value (and
// atomically re-arms the slot). Each address has ONE reader and ONE writer;
// values strictly alternate SENT <-> fresh because a wg only reaches step
// s+2 (next write of this phase) after observing complete h_{s+1}, which
// happens only after every consumer's poll-RMW of phase s&1 completed at
// the coherence point. No waitcnt asm needed: all ordering is carried by
// RMW data dependences.
// ---------------------------------------------------------------------------
#define SENT 0xAAAAAAAAu

__global__ __launch_bounds__(512, 2) void rnn_scan_sync(
        const float* __restrict__ W_hh, const float* __restrict__ h0,
        float* __restrict__ out, unsigned* __restrict__ mb) {
    const int slice = blockIdx.x;      // 0..3  (this wg's column slice)
    const int b     = blockIdx.y;      // 0..63
    const int t     = threadIdx.x;     // 0..511
    const int q     = t >> 7;          // 0..3
    const int j     = t & 127;         // 0..127
    const int col   = slice * 128 + j; // this thread's output column (t<... all)

    __shared__ float h_lds[H_DIM];
    __shared__ float part[4][128];
    __shared__ float hn_s[128];

    // One-time W load: thread t holds W_hh[col][q*128 .. q*128+127].
    float w[128];
    {
        const float* wrow = W_hh + (size_t)col * H_DIM + q * 128;
#pragma unroll
        for (int k = 0; k < 128; k += 4) {
            float4 v = *(const float4*)(wrow + k);
            w[k + 0] = v.x; w[k + 1] = v.y; w[k + 2] = v.z; w[k + 3] = v.w;
        }
    }

    h_lds[t] = h0[(size_t)b * H_DIM + t];
    __syncthreads();

    float* outb = out + (size_t)b * (size_t)S_LEN * H_DIM;
    bool alive = true;

    for (int s = 0; s < S_LEN; ++s) {
        // Prefetch xp (overlaps the poll below).
        float xp = 0.f;
        if (t < 128) xp = outb[(size_t)s * H_DIM + slice * 128 + t];

        if (s > 0) {
            const int ph = (s - 1) & 1;
            unsigned* src = mb + (((size_t)ph * 4 + slice) * B_SZ + b) * H_DIM + t;
            unsigned v = SENT;
            if (alive) {
                int iters = 0;
                do {
                    v = atomicExch(src, SENT);   // real RMW; auto-re-arms slot
                    if (v != SENT) break;
                } while (++iters < 4000000);
                if (v == SENT) alive = false;    // bail instead of hanging
            }
            h_lds[t] = __uint_as_float(v);
            __syncthreads();
        }

        // Partial dot: 128 register-FMAs vs LDS h segment, 4 accumulators.
        const float* hs = &h_lds[q * 128];
        float a0 = 0.f, a1 = 0.f, a2 = 0.f, a3 = 0.f;
#pragma unroll
        for (int k = 0; k < 128; k += 4) {
            a0 = fmaf(w[k + 0], hs[k + 0], a0);
            a1 = fmaf(w[k + 1], hs[k + 1], a1);
            a2 = fmaf(w[k + 2], hs[k + 2], a2);
            a3 = fmaf(w[k + 3], hs[k + 3], a3);
        }
        part[q][j] = (a0 + a1) + (a2 + a3);
        __syncthreads();

        if (t < 128) {
            float z  = xp + part[0][t] + part[1][t] + part[2][t] + part[3][t];
            float hn = tanhf(z);
            hn_s[t] = hn;
            outb[(size_t)s * H_DIM + slice * 128 + t] = hn;
        }
        __syncthreads();

        // Publish: all 512 threads push hn_s to consumer mailbox q (= t>>7).
        {
            const int ph = s & 1;
            unsigned* dst = mb + (((size_t)ph * 4 + q) * B_SZ + b) * H_DIM
                               + slice * 128 + j;
            atomicExch(dst, __float_as_uint(hn_s[j]));
        }
        // No trailing barrier needed: next iteration's h_lds write is gated
        // by the post-poll __syncthreads before any thread's FMA reads it.
    }
}

// ---------------------------------------------------------------------------
extern "C" void kernel_launch(void* const* d_in, const int* in_sizes, int n_in,
                              void* d_out, int out_size, void* d_ws, size_t ws_size,
                              hipStream_t stream) {
    const float* x_in = (const float*)d_in[0];
    const float* h0   = (const float*)d_in[1];
    const float* W_ih = (const float*)d_in[2];
    const float* W_hh = (const float*)d_in[3];
    const float* b_ih = (const float*)d_in[4];
    const float* b_hh = (const float*)d_in[5];
    float* out   = (float*)d_out;
    unsigned* mb = (unsigned*)d_ws;   // 2*4*64*512*4 = 1 MB

    // 1) x_proj (+biases) straight into d_out.
    dim3 gA(H_DIM / BN, (B_SZ * S_LEN) / BM);
    proj_gemm<<<gA, 256, 0, stream>>>(x_in, W_ih, b_ih, b_hh, out);

    // 2) Arm all mailboxes with the sentinel (matches harness 0xAA poison,
    //    but do it explicitly: phase-1 mailbox retains data at kernel exit).
    hipMemsetAsync(d_ws, 0xAA, (size_t)2 * 4 * B_SZ * H_DIM * sizeof(unsigned),
                   stream);

    // 3) Register-resident scan: 64 batches x 4 column-slices = 256 wgs.
    rnn_scan_sync<<<dim3(4, B_SZ), 512, 0, stream>>>(W_hh, h0, out, mb);
}